// Round 2
// baseline (315.719 us; speedup 1.0000x reference)
//
#include <hip/hip_runtime.h>
#include <cstdint>
#include <cstddef>

typedef __bf16 bf16;
typedef __bf16 bf16x8 __attribute__((ext_vector_type(8)));
typedef __bf16 bf16x4 __attribute__((ext_vector_type(4)));
typedef float  f32x4  __attribute__((ext_vector_type(4)));

#define C_EPS 1e-5f
#define NB_ 8
#define NC_ 64
#define NH_ 256
#define NW_ 256
#define HP_ (NH_*NW_)

// workspace layout (bytes)
#define OFF_H    0ull                 // h: 8*256*256*64 bf16 = 67108864 B
#define OFF_EDGE 67108864ull          // edge: 8*128*128*64 bf16 = 16777216 B
#define OFF_W1   83886080ull          // packed w1: 36864 bf16 = 73728 B
#define OFF_W2   83959808ull          // packed w2
#define OFF_AFF  84033536ull          // alpha1[64],beta1[64],alpha2[64],beta2[64] f32

// swizzled LDS byte offset for [pixel p][ci] bf16 tile, 16B-granule XOR swizzle.
// pixel stride = 128 B (64 ci * 2 B) == 32 banks -> must swizzle.
__device__ __forceinline__ int lds_off(int p, int cib) {
    return p * 128 + (((cib) ^ (p & 7)) << 4);
}

// ---------------------------------------------------------------------------
// pack weights into MFMA B-frag order + BN affine fold
// packed index u = (((tap*2+kb)*4+nb)*64 + lane)*8 + j
//   lane holds w[co = nb*16 + (lane&15)][ci = kb*32 + (lane>>4)*8 + j][tap]
__global__ void k_pack(const float* __restrict__ w1, const float* __restrict__ w2,
                       const float* __restrict__ b1, const float* __restrict__ g1,
                       const float* __restrict__ be1, const float* __restrict__ m1,
                       const float* __restrict__ v1,
                       const float* __restrict__ b2, const float* __restrict__ g2,
                       const float* __restrict__ be2, const float* __restrict__ m2,
                       const float* __restrict__ v2,
                       bf16* __restrict__ wp1, bf16* __restrict__ wp2,
                       float* __restrict__ aff)
{
    int idx = blockIdx.x * 256 + threadIdx.x;
    if (idx < 2 * 36864) {
        int conv = idx / 36864;
        int u = idx - conv * 36864;
        int j  = u & 7;
        int l  = (u >> 3) & 63;
        int nb = (u >> 9) & 3;
        int kb = (u >> 11) & 1;
        int t  = u >> 12;                  // 0..8
        int co = nb * 16 + (l & 15);
        int ci = kb * 32 + ((l >> 4) << 3) + j;
        const float* w = conv ? w2 : w1;
        float val = w[(co * 64 + ci) * 9 + t];
        (conv ? wp2 : wp1)[u] = (bf16)val;
    } else {
        int c = idx - 2 * 36864;
        if (c < 64) {
            float s = g1[c] / sqrtf(v1[c] + C_EPS);
            aff[c]      = s;
            aff[64 + c] = b1[c] * s + (be1[c] - m1[c] * s);
        } else if (c < 128) {
            int cc = c - 64;
            float s = g2[cc] / sqrtf(v2[cc] + C_EPS);
            aff[128 + cc] = s;
            aff[192 + cc] = b2[cc] * s + (be2[cc] - m2[cc] * s);
        }
    }
}

// ---------------------------------------------------------------------------
// conv1 + BN1 + PReLU -> h (NHWC bf16); also Haar edge (half-res NHWC bf16)
// GEMM roles: M = co (so h-store packs 4 consecutive co), N = pixels, K = ci
__global__ __launch_bounds__(256, 3)
void k_conv1(const float* __restrict__ x, const bf16* __restrict__ wp,
             const float* __restrict__ aff, const float* __restrict__ aprelu,
             bf16* __restrict__ h, bf16* __restrict__ edge)
{
    __shared__ uint4 smem[2592];               // 41472 B: 324 pixels * 128 B
    char* sh = reinterpret_cast<char*>(smem);
    const int t = threadIdx.x;
    const int x0 = blockIdx.x * 16, y0 = blockIdx.y * 16;
    const int bb = blockIdx.z;
    const float* xb = x + (size_t)bb * NC_ * HP_;

    // stage 18x18 halo x 64 ci (4 ci per item -> ds_write_b64)
    for (int i = 0; i < 21; ++i) {
        int item = i * 256 + t;
        if (item < 5184) {
            int ci4 = item / 324;              // 0..15
            int p   = item - ci4 * 324;        // 0..323
            int r   = p / 18;
            int c   = p - r * 18;
            int yy = y0 - 1 + r, xx = x0 - 1 + c;
            float v0 = 0.f, v1 = 0.f, v2 = 0.f, v3 = 0.f;
            if (yy >= 0 && yy < NH_ && xx >= 0 && xx < NW_) {
                const float* s = xb + (size_t)(ci4 * 4) * HP_ + yy * NW_ + xx;
                v0 = s[0]; v1 = s[HP_]; v2 = s[2 * HP_]; v3 = s[3 * HP_];
            }
            bf16x4 pk = { (bf16)v0, (bf16)v1, (bf16)v2, (bf16)v3 };
            int off = lds_off(p, ci4 >> 1) + ((ci4 & 1) << 3);
            *reinterpret_cast<bf16x4*>(sh + off) = pk;
        }
    }
    __syncthreads();

    // Haar edge for this tile's 8x8 half-res block, all 64 ci
    {
        int ci = t & 63;
        int q  = t >> 6;
        int cib = ci >> 3, cio = (ci & 7) << 1;
        #pragma unroll
        for (int i = 0; i < 16; ++i) {
            int hp = i * 4 + q;                 // 0..63
            int yh = hp >> 3, xh = hp & 7;
            int pA = (2 * yh + 1) * 18 + (2 * xh + 1);
            float a  = (float)*reinterpret_cast<const bf16*>(sh + lds_off(pA,      cib) + cio);
            float b_ = (float)*reinterpret_cast<const bf16*>(sh + lds_off(pA + 1,  cib) + cio);
            float c_ = (float)*reinterpret_cast<const bf16*>(sh + lds_off(pA + 18, cib) + cio);
            float d_ = (float)*reinterpret_cast<const bf16*>(sh + lds_off(pA + 19, cib) + cio);
            float e = (3.f * a - b_ - c_ - d_) * 0.5f;
            edge[(((size_t)bb * 128 + (y0 >> 1) + yh) * 128 + (x0 >> 1) + xh) * 64 + ci] = (bf16)e;
        }
    }

    const int w = t >> 6, l = t & 63;
    const int l15 = l & 15, lg = l >> 4;
    f32x4 acc[4][4];
    #pragma unroll
    for (int a = 0; a < 4; ++a)
        #pragma unroll
        for (int b = 0; b < 4; ++b) acc[a][b] = f32x4{0.f, 0.f, 0.f, 0.f};

    const bf16x8* wv = reinterpret_cast<const bf16x8*>(wp);
    #pragma unroll
    for (int ky = 0; ky < 3; ++ky)
    #pragma unroll
    for (int kx = 0; kx < 3; ++kx)
    #pragma unroll
    for (int kb = 0; kb < 2; ++kb) {
        const int tap = ky * 3 + kx;
        bf16x8 wf[4];
        #pragma unroll
        for (int cb = 0; cb < 4; ++cb)
            wf[cb] = wv[(((tap * 2 + kb) * 4 + cb) << 6) + l];
        #pragma unroll
        for (int pr = 0; pr < 4; ++pr) {
            int p = (w * 4 + pr + ky) * 18 + (l15 + kx);
            bf16x8 xf = *reinterpret_cast<const bf16x8*>(sh + lds_off(p, kb * 4 + lg));
            #pragma unroll
            for (int cb = 0; cb < 4; ++cb)
                acc[cb][pr] = __builtin_amdgcn_mfma_f32_16x16x32_bf16(wf[cb], xf, acc[cb][pr], 0, 0, 0);
        }
    }

    // epilogue: BN + PReLU, store NHWC bf16 (4 consecutive co packed per store)
    const float apv = aprelu[0];
    f32x4 al[4], be_[4];
    #pragma unroll
    for (int cb = 0; cb < 4; ++cb) {
        al[cb]  = *reinterpret_cast<const f32x4*>(aff + cb * 16 + lg * 4);
        be_[cb] = *reinterpret_cast<const f32x4*>(aff + 64 + cb * 16 + lg * 4);
    }
    #pragma unroll
    for (int pr = 0; pr < 4; ++pr) {
        const int Y = y0 + w * 4 + pr;
        const int X = x0 + l15;
        bf16* hp_ = h + (((size_t)bb * NH_ + Y) * NW_ + X) * 64 + lg * 4;
        #pragma unroll
        for (int cb = 0; cb < 4; ++cb) {
            bf16x4 pk;
            #pragma unroll
            for (int r = 0; r < 4; ++r) {
                float zv = acc[cb][pr][r] * al[cb][r] + be_[cb][r];
                float hv = zv > 0.f ? zv : apv * zv;
                pk[r] = (bf16)hv;
            }
            *reinterpret_cast<bf16x4*>(hp_ + cb * 16) = pk;
        }
    }
}

// ---------------------------------------------------------------------------
// conv2 + BN2 + x + bilinear(edge) -> out (NCHW f32)
// GEMM roles: M = pixels (so out-store is float4 along W), N = co, K = ci
// LDS: h halo 41472 B + staged half-res edge 12800 B = 54272 B -> 3 blocks/CU
__global__ __launch_bounds__(256, 3)
void k_conv2(const bf16* __restrict__ h, const bf16* __restrict__ wp,
             const float* __restrict__ aff, const float* __restrict__ x,
             const bf16* __restrict__ edge, float* __restrict__ out)
{
    __shared__ uint4 smem[3392];               // 54272 B
    char* sh = reinterpret_cast<char*>(smem);            // h halo: 324 px * 128 B
    char* se = reinterpret_cast<char*>(smem) + 41472;    // edge: 100 px * 128 B
    const int t = threadIdx.x;
    const int x0 = blockIdx.x * 16, y0 = blockIdx.y * 16;
    const int bb = blockIdx.z;

    // stage h halo (NHWC bf16): 324 pixels x 8 chunks of 16 B -> ds_write_b128
    for (int i = 0; i < 11; ++i) {
        int item = i * 256 + t;
        if (item < 2592) {
            int cib = item & 7;
            int p   = item >> 3;
            int r = p / 18;
            int c = p - r * 18;
            int yy = y0 - 1 + r, xx = x0 - 1 + c;
            uint4 v = {0u, 0u, 0u, 0u};
            if (yy >= 0 && yy < NH_ && xx >= 0 && xx < NW_)
                v = *reinterpret_cast<const uint4*>(h + (((size_t)bb * NH_ + yy) * NW_ + xx) * 64 + cib * 8);
            *reinterpret_cast<uint4*>(sh + lds_off(p, cib)) = v;
        }
    }
    // stage 10x10 half-res edge region (clamped indices; clamped duplicate taps
    // make the bilinear boundary math come out exactly like jax's clamp)
    for (int i = 0; i < 4; ++i) {
        int item = i * 256 + t;
        if (item < 800) {
            int cib = item & 7;
            int p   = item >> 3;               // 0..99
            int ry = p / 10, rx = p - ry * 10;
            int ryg = (y0 >> 1) - 1 + ry;
            int rxg = (x0 >> 1) - 1 + rx;
            ryg = ryg < 0 ? 0 : (ryg > 127 ? 127 : ryg);
            rxg = rxg < 0 ? 0 : (rxg > 127 ? 127 : rxg);
            uint4 v = *reinterpret_cast<const uint4*>(
                edge + (((size_t)bb * 128 + ryg) * 128 + rxg) * 64 + cib * 8);
            *reinterpret_cast<uint4*>(se + lds_off(p, cib)) = v;
        }
    }
    __syncthreads();

    const int w = t >> 6, l = t & 63;
    const int l15 = l & 15, lg = l >> 4;
    f32x4 acc[4][4];
    #pragma unroll
    for (int a = 0; a < 4; ++a)
        #pragma unroll
        for (int b = 0; b < 4; ++b) acc[a][b] = f32x4{0.f, 0.f, 0.f, 0.f};

    const bf16x8* wv = reinterpret_cast<const bf16x8*>(wp);
    #pragma unroll
    for (int ky = 0; ky < 3; ++ky)
    #pragma unroll
    for (int kx = 0; kx < 3; ++kx)
    #pragma unroll
    for (int kb = 0; kb < 2; ++kb) {
        const int tap = ky * 3 + kx;
        bf16x8 wf[4];
        #pragma unroll
        for (int cb = 0; cb < 4; ++cb)
            wf[cb] = wv[(((tap * 2 + kb) * 4 + cb) << 6) + l];
        #pragma unroll
        for (int pr = 0; pr < 4; ++pr) {
            int p = (w * 4 + pr + ky) * 18 + (l15 + kx);
            bf16x8 xf = *reinterpret_cast<const bf16x8*>(sh + lds_off(p, kb * 4 + lg));
            #pragma unroll
            for (int cb = 0; cb < 4; ++cb)
                acc[pr][cb] = __builtin_amdgcn_mfma_f32_16x16x32_bf16(xf, wf[cb], acc[pr][cb], 0, 0, 0);
        }
    }

    // epilogue: BN2 + x + bilinear(edge from LDS), float4 stores (NCHW).
    // Thread's 4x4 output pixels (rows y0+4w+pr, cols x0+4lg+rr) need the 4x4
    // half-res tap grid at local rows 2w..2w+3, cols 2lg..2lg+3.
    // pr/rr (both start even): tap pair (k,k+1), low-weight table {.25,.75,.25,.75},
    // pair base {0,1,1,2}.
    #pragma unroll
    for (int cb = 0; cb < 4; ++cb) {
        const int co = cb * 16 + l15;
        const int cib2 = co >> 3;
        const int cio = (co & 7) << 1;
        float et[4][4];
        #pragma unroll
        for (int r = 0; r < 4; ++r)
            #pragma unroll
            for (int c = 0; c < 4; ++c) {
                int ep = (2 * w + r) * 10 + (2 * lg + c);
                et[r][c] = (float)*reinterpret_cast<const bf16*>(se + lds_off(ep, cib2) + cio);
            }
        const float al = aff[128 + co];
        const float bt = aff[192 + co];
        const float* xs0 = x + ((size_t)bb * NC_ + co) * HP_;
        #pragma unroll
        for (int pr = 0; pr < 4; ++pr) {
            const int Y = y0 + w * 4 + pr;
            const int Xb = x0 + lg * 4;
            const int ry0 = (pr == 0) ? 0 : (pr == 3 ? 2 : 1);
            const float wyl = (pr & 1) ? 0.75f : 0.25f;
            f32x4 xq = *reinterpret_cast<const f32x4*>(xs0 + Y * NW_ + Xb);
            f32x4 o;
            #pragma unroll
            for (int rr = 0; rr < 4; ++rr) {
                const int rx0 = (rr == 0) ? 0 : (rr == 3 ? 2 : 1);
                const float wxl = (rr & 1) ? 0.75f : 0.25f;
                float e0 = wxl * et[ry0][rx0]     + (1.f - wxl) * et[ry0][rx0 + 1];
                float e1 = wxl * et[ry0 + 1][rx0] + (1.f - wxl) * et[ry0 + 1][rx0 + 1];
                float e  = wyl * e0 + (1.f - wyl) * e1;
                o[rr] = acc[pr][cb][rr] * al + bt + xq[rr] + e;
            }
            float* os = out + ((size_t)bb * NC_ + co) * HP_ + Y * NW_ + Xb;
            *reinterpret_cast<f32x4*>(os) = o;
        }
    }
}

// ---------------------------------------------------------------------------
extern "C" void kernel_launch(void* const* d_in, const int* in_sizes, int n_in,
                              void* d_out, int out_size, void* d_ws, size_t ws_size,
                              hipStream_t stream)
{
    const float* x   = (const float*)d_in[0];
    const float* w1  = (const float*)d_in[1];
    const float* b1  = (const float*)d_in[2];
    const float* g1  = (const float*)d_in[3];
    const float* be1 = (const float*)d_in[4];
    const float* m1  = (const float*)d_in[5];
    const float* v1  = (const float*)d_in[6];
    const float* ap  = (const float*)d_in[7];
    const float* w2  = (const float*)d_in[8];
    const float* b2  = (const float*)d_in[9];
    const float* g2  = (const float*)d_in[10];
    const float* be2 = (const float*)d_in[11];
    const float* m2  = (const float*)d_in[12];
    const float* v2  = (const float*)d_in[13];

    char* ws = (char*)d_ws;
    bf16*  hbuf = (bf16*)(ws + OFF_H);
    bf16*  ebuf = (bf16*)(ws + OFF_EDGE);
    bf16*  wp1  = (bf16*)(ws + OFF_W1);
    bf16*  wp2  = (bf16*)(ws + OFF_W2);
    float* aff  = (float*)(ws + OFF_AFF);
    float* outp = (float*)d_out;

    k_pack<<<dim3(290), dim3(256), 0, stream>>>(w1, w2, b1, g1, be1, m1, v1,
                                                b2, g2, be2, m2, v2, wp1, wp2, aff);
    k_conv1<<<dim3(16, 16, 8), dim3(256), 0, stream>>>(x, wp1, aff, ap, hbuf, ebuf);
    k_conv2<<<dim3(16, 16, 8), dim3(256), 0, stream>>>(hbuf, wp2, aff, x, ebuf, outp);
}

// Round 4
// 186.338 us; speedup vs baseline: 1.6943x; 1.6943x over previous
//
#include <hip/hip_runtime.h>
#include <cstdint>
#include <cstddef>

typedef __bf16 bf16;
typedef __bf16 bf16x8 __attribute__((ext_vector_type(8)));
typedef __bf16 bf16x4 __attribute__((ext_vector_type(4)));
typedef float  f32x4  __attribute__((ext_vector_type(4)));

#define C_EPS 1e-5f
#define NC_ 64
#define NH_ 256
#define NW_ 256
#define HP_ (NH_*NW_)

// workspace layout (bytes)
#define OFF_W1   0ull
#define OFF_W2   73728ull
#define OFF_AFF  147456ull

// swizzled LDS byte offset for [pixel p][ci] bf16 tile (128 B per pixel row),
// 16-B-granule XOR swizzle: pixel stride 128 B == 32 banks -> must swizzle.
__device__ __forceinline__ int lds_off(int p, int cib) {
    return p * 128 + (((cib) ^ (p & 7)) << 4);
}

// ---------------------------------------------------------------------------
// pack weights into MFMA B-frag order + BN affine fold
// packed index u = (((tap*2+kb)*4+nb)*64 + lane)*8 + j
//   lane holds w[co = nb*16 + (lane&15)][ci = kb*32 + (lane>>4)*8 + j][tap]
__global__ void k_pack(const float* __restrict__ w1, const float* __restrict__ w2,
                       const float* __restrict__ b1, const float* __restrict__ g1,
                       const float* __restrict__ be1, const float* __restrict__ m1,
                       const float* __restrict__ v1,
                       const float* __restrict__ b2, const float* __restrict__ g2,
                       const float* __restrict__ be2, const float* __restrict__ m2,
                       const float* __restrict__ v2,
                       bf16* __restrict__ wp1, bf16* __restrict__ wp2,
                       float* __restrict__ aff)
{
    int idx = blockIdx.x * 256 + threadIdx.x;
    if (idx < 2 * 36864) {
        int conv = idx / 36864;
        int u = idx - conv * 36864;
        int j  = u & 7;
        int l  = (u >> 3) & 63;
        int nb = (u >> 9) & 3;
        int kb = (u >> 11) & 1;
        int t  = u >> 12;                  // 0..8
        int co = nb * 16 + (l & 15);
        int ci = kb * 32 + ((l >> 4) << 3) + j;
        const float* w = conv ? w2 : w1;
        float val = w[(co * 64 + ci) * 9 + t];
        (conv ? wp2 : wp1)[u] = (bf16)val;
    } else {
        int c = idx - 2 * 36864;
        if (c < 64) {
            float s = g1[c] / sqrtf(v1[c] + C_EPS);
            aff[c]      = s;
            aff[64 + c] = b1[c] * s + (be1[c] - m1[c] * s);
        } else if (c < 128) {
            int cc = c - 64;
            float s = g2[cc] / sqrtf(v2[cc] + C_EPS);
            aff[128 + cc] = s;
            aff[192 + cc] = b2[cc] * s + (be2[cc] - m2[cc] * s);
        }
    }
}

// ---------------------------------------------------------------------------
// Fully fused: stage x(20x20 halo) -> edge taps -> conv1+BN1+PReLU (18x18 h,
// LDS-resident, overwrites x; h zeroed outside the image = conv2 SAME padding)
// -> conv2+BN2 + x + bilinear(edge) -> out.
// LDS: [0,51200) x tile then h tile (aliased); [51200,64000) edge 10x10.
__global__ __launch_bounds__(256, 2)
void k_fused(const float* __restrict__ x, const bf16* __restrict__ wp1,
             const bf16* __restrict__ wp2, const float* __restrict__ aff,
             const float* __restrict__ aprelu, float* __restrict__ out)
{
    __shared__ uint4 smem[4000];                 // 64000 B
    char* sx = reinterpret_cast<char*>(smem);            // x then h
    char* se = reinterpret_cast<char*>(smem) + 51200;    // edge taps
    const int t = threadIdx.x;

    // XCD-bijective swizzle (2048 blocks, 8 XCDs): each XCD owns one image
    const int bid = blockIdx.x;
    const int logical = (bid & 7) * 256 + (bid >> 3);
    const int x0 = (logical & 15) * 16;
    const int y0 = ((logical >> 4) & 15) * 16;
    const int bb = logical >> 8;
    const float* xb = x + (size_t)bb * NC_ * HP_;

    // ---- phase 1: stage x 20x20 halo (origin y0-2, x0-2) x 64 ci as bf16
    for (int i = 0; i < 25; ++i) {
        int item = i * 256 + t;                  // 6400 = 16 ci4 * 400 px
        int ci4 = item / 400;
        int p   = item - ci4 * 400;
        int r = p / 20, c = p - r * 20;
        int yy = y0 - 2 + r, xx = x0 - 2 + c;
        float v0 = 0.f, v1 = 0.f, v2 = 0.f, v3 = 0.f;
        if (yy >= 0 && yy < NH_ && xx >= 0 && xx < NW_) {
            const float* s = xb + (size_t)(ci4 * 4) * HP_ + yy * NW_ + xx;
            v0 = s[0]; v1 = s[HP_]; v2 = s[2 * HP_]; v3 = s[3 * HP_];
        }
        bf16x4 pk = { (bf16)v0, (bf16)v1, (bf16)v2, (bf16)v3 };
        *reinterpret_cast<bf16x4*>(sx + lds_off(p, ci4 >> 1) + ((ci4 & 1) << 3)) = pk;
    }
    __syncthreads();

    // ---- phase 2a: edge taps 10x10 half-res x 64 ch (reads x LDS -> se)
    for (int i = 0; i < 25; ++i) {
        int unit = i * 256 + t;                  // 6400 = 100 hp * 64 ci
        int ci = unit & 63;
        int hp = unit >> 6;
        int ry = hp / 10, rx = hp - ry * 10;
        int ryg = (y0 >> 1) - 1 + ry; ryg = ryg < 0 ? 0 : (ryg > 127 ? 127 : ryg);
        int rxg = (x0 >> 1) - 1 + rx; rxg = rxg < 0 ? 0 : (rxg > 127 ? 127 : rxg);
        int pA = (2 * ryg - y0 + 2) * 20 + (2 * rxg - x0 + 2);
        int cib = ci >> 3, cio = (ci & 7) << 1;
        float a  = (float)*reinterpret_cast<const bf16*>(sx + lds_off(pA,      cib) + cio);
        float b_ = (float)*reinterpret_cast<const bf16*>(sx + lds_off(pA + 1,  cib) + cio);
        float c_ = (float)*reinterpret_cast<const bf16*>(sx + lds_off(pA + 20, cib) + cio);
        float d_ = (float)*reinterpret_cast<const bf16*>(sx + lds_off(pA + 21, cib) + cio);
        *reinterpret_cast<bf16*>(se + lds_off(hp, cib) + cio) =
            (bf16)((3.f * a - b_ - c_ - d_) * 0.5f);
    }

    // ---- phase 2b: conv1 MFMAs -> 18x18 h in registers
    const int w = t >> 6, l = t & 63;
    const int l15 = l & 15, lg = l >> 4;
    f32x4 acc1[6][4];
    #pragma unroll
    for (int j = 0; j < 6; ++j)
        #pragma unroll
        for (int cb = 0; cb < 4; ++cb) acc1[j][cb] = f32x4{0.f, 0.f, 0.f, 0.f};

    int prj[6], pcj[6];
    #pragma unroll
    for (int j = 0; j < 6; ++j) {
        int g = w + 4 * j;
        int p = g * 16 + l15; if (p > 323) p = 323;   // addr-safe clamp
        prj[j] = p / 18; pcj[j] = p - prj[j] * 18;
    }

    const bf16x8* wv1 = reinterpret_cast<const bf16x8*>(wp1);
    #pragma unroll
    for (int ky = 0; ky < 3; ++ky)
    #pragma unroll
    for (int kx = 0; kx < 3; ++kx)
    #pragma unroll
    for (int kb = 0; kb < 2; ++kb) {
        const int tap = ky * 3 + kx;
        bf16x8 wf[4];
        #pragma unroll
        for (int cb = 0; cb < 4; ++cb)
            wf[cb] = wv1[(((tap * 2 + kb) * 4 + cb) << 6) + l];
        #pragma unroll
        for (int j = 0; j < 6; ++j) {
            if (w + 4 * j > 20) continue;        // wave-uniform guard
            bf16x8 xf = *reinterpret_cast<const bf16x8*>(
                sx + lds_off((prj[j] + ky) * 20 + pcj[j] + kx, kb * 4 + lg));
            #pragma unroll
            for (int cb = 0; cb < 4; ++cb)
                acc1[j][cb] = __builtin_amdgcn_mfma_f32_16x16x32_bf16(wf[cb], xf, acc1[j][cb], 0, 0, 0);
        }
    }
    __syncthreads();                             // all x-LDS reads complete

    // ---- phase 3: BN1 + PReLU, write h over x region ([px 0..323][co]).
    // h pixels whose GLOBAL coords fall outside the image must be ZERO
    // (conv2's SAME padding pads h with zeros) — not conv1-of-padded-x.
    {
        const float apv = aprelu[0];
        #pragma unroll
        for (int j = 0; j < 6; ++j) {
            int g = w + 4 * j;
            if (g > 20) continue;
            int p = g * 16 + l15;
            if (p < 324) {
                const int hy = y0 - 1 + prj[j];
                const int hx = x0 - 1 + pcj[j];
                const bool valid = (hy >= 0) && (hy < NH_) && (hx >= 0) && (hx < NW_);
                #pragma unroll
                for (int cb = 0; cb < 4; ++cb) {
                    f32x4 al = *reinterpret_cast<const f32x4*>(aff + cb * 16 + lg * 4);
                    f32x4 be = *reinterpret_cast<const f32x4*>(aff + 64 + cb * 16 + lg * 4);
                    bf16x4 pk;
                    #pragma unroll
                    for (int r = 0; r < 4; ++r) {
                        float zv = acc1[j][cb][r] * al[r] + be[r];
                        float hv = zv > 0.f ? zv : apv * zv;
                        pk[r] = valid ? (bf16)hv : (bf16)0.f;
                    }
                    *reinterpret_cast<bf16x4*>(sx + lds_off(p, cb * 2 + (lg >> 1)) + ((lg & 1) << 3)) = pk;
                }
            }
        }
    }
    __syncthreads();                             // h tile visible to all

    // ---- phase 4: conv2 MFMAs (M = pixels, N = co)
    f32x4 acc2[4][4];
    #pragma unroll
    for (int a = 0; a < 4; ++a)
        #pragma unroll
        for (int b = 0; b < 4; ++b) acc2[a][b] = f32x4{0.f, 0.f, 0.f, 0.f};

    const bf16x8* wv2 = reinterpret_cast<const bf16x8*>(wp2);
    #pragma unroll
    for (int ky = 0; ky < 3; ++ky)
    #pragma unroll
    for (int kx = 0; kx < 3; ++kx)
    #pragma unroll
    for (int kb = 0; kb < 2; ++kb) {
        const int tap = ky * 3 + kx;
        bf16x8 wf[4];
        #pragma unroll
        for (int cb = 0; cb < 4; ++cb)
            wf[cb] = wv2[(((tap * 2 + kb) * 4 + cb) << 6) + l];
        #pragma unroll
        for (int pr = 0; pr < 4; ++pr) {
            int p = (w * 4 + pr + ky) * 18 + (l15 + kx);
            bf16x8 xf = *reinterpret_cast<const bf16x8*>(sx + lds_off(p, kb * 4 + lg));
            #pragma unroll
            for (int cb = 0; cb < 4; ++cb)
                acc2[pr][cb] = __builtin_amdgcn_mfma_f32_16x16x32_bf16(xf, wf[cb], acc2[pr][cb], 0, 0, 0);
        }
    }

    // ---- phase 5: BN2 + x (global, L2-hot) + bilinear(edge LDS), f32x4 stores
    #pragma unroll
    for (int cb = 0; cb < 4; ++cb) {
        const int co = cb * 16 + l15;
        const int cib2 = co >> 3;
        const int cio = (co & 7) << 1;
        float et[4][4];
        #pragma unroll
        for (int r = 0; r < 4; ++r)
            #pragma unroll
            for (int c = 0; c < 4; ++c) {
                int ep = (2 * w + r) * 10 + (2 * lg + c);
                et[r][c] = (float)*reinterpret_cast<const bf16*>(se + lds_off(ep, cib2) + cio);
            }
        const float al = aff[128 + co];
        const float bt = aff[192 + co];
        const float* xs0 = x + ((size_t)bb * NC_ + co) * HP_;
        #pragma unroll
        for (int pr = 0; pr < 4; ++pr) {
            const int Y = y0 + w * 4 + pr;
            const int Xb = x0 + lg * 4;
            const int ry0 = (pr == 0) ? 0 : (pr == 3 ? 2 : 1);
            const float wyl = (pr & 1) ? 0.75f : 0.25f;
            f32x4 xq = *reinterpret_cast<const f32x4*>(xs0 + Y * NW_ + Xb);
            f32x4 o;
            #pragma unroll
            for (int rr = 0; rr < 4; ++rr) {
                const int rx0 = (rr == 0) ? 0 : (rr == 3 ? 2 : 1);
                const float wxl = (rr & 1) ? 0.75f : 0.25f;
                float e0 = wxl * et[ry0][rx0]     + (1.f - wxl) * et[ry0][rx0 + 1];
                float e1 = wxl * et[ry0 + 1][rx0] + (1.f - wxl) * et[ry0 + 1][rx0 + 1];
                float e  = wyl * e0 + (1.f - wyl) * e1;
                o[rr] = acc2[pr][cb][rr] * al + bt + xq[rr] + e;
            }
            float* os = out + ((size_t)bb * NC_ + co) * HP_ + Y * NW_ + Xb;
            *reinterpret_cast<f32x4*>(os) = o;
        }
    }
}

// ---------------------------------------------------------------------------
extern "C" void kernel_launch(void* const* d_in, const int* in_sizes, int n_in,
                              void* d_out, int out_size, void* d_ws, size_t ws_size,
                              hipStream_t stream)
{
    const float* x   = (const float*)d_in[0];
    const float* w1  = (const float*)d_in[1];
    const float* b1  = (const float*)d_in[2];
    const float* g1  = (const float*)d_in[3];
    const float* be1 = (const float*)d_in[4];
    const float* m1  = (const float*)d_in[5];
    const float* v1  = (const float*)d_in[6];
    const float* ap  = (const float*)d_in[7];
    const float* w2  = (const float*)d_in[8];
    const float* b2  = (const float*)d_in[9];
    const float* g2  = (const float*)d_in[10];
    const float* be2 = (const float*)d_in[11];
    const float* m2  = (const float*)d_in[12];
    const float* v2  = (const float*)d_in[13];

    char* ws = (char*)d_ws;
    bf16*  wp1  = (bf16*)(ws + OFF_W1);
    bf16*  wp2  = (bf16*)(ws + OFF_W2);
    float* aff  = (float*)(ws + OFF_AFF);
    float* outp = (float*)d_out;

    k_pack<<<dim3(290), dim3(256), 0, stream>>>(w1, w2, b1, g1, be1, m1, v1,
                                                b2, g2, be2, m2, v2, wp1, wp2, aff);
    k_fused<<<dim3(2048), dim3(256), 0, stream>>>(x, wp1, wp2, aff, ap, outp);
}